// Round 4
// baseline (299.328 us; speedup 1.0000x reference)
//
#include <hip/hip_runtime.h>
#include <math.h>

typedef __attribute__((ext_vector_type(8))) short short8;
typedef __attribute__((ext_vector_type(4))) float floatx4;

#define NB    4
#define CIN   64
#define COUT  128
#define IMH   128
#define IMW   256
#define KTOT  576
#define NPIX  (IMH * IMW)
#define PXT   128
#define NDPB  (PXT * 9)          // 1152 descriptors per block
#define STG_ROW  134             // words per staged row (128 data + pad)
#define STG_COPY (5 * STG_ROW)   // 670
#define STG_CH   (2 * STG_COPY)  // 1340 words per channel

__device__ __forceinline__ unsigned short f2bf(float f) {
  union { float f; unsigned u; } v; v.f = f;
  return (unsigned short)((v.u + 0x7FFFu + ((v.u >> 16) & 1u)) >> 16);
}
__device__ __forceinline__ unsigned pk2(float lo, float hi) {
  return (unsigned)f2bf(lo) | ((unsigned)f2bf(hi) << 16);
}
__device__ __forceinline__ float bfl(unsigned w) {
  union { unsigned u; float f; } v; v.u = w << 16; return v.f;
}
__device__ __forceinline__ float bfh(unsigned w) {
  union { unsigned u; float f; } v; v.u = w & 0xFFFF0000u; return v.f;
}
__device__ __forceinline__ unsigned pkf16(float a, float b) {
  _Float16 ha = (_Float16)a, hb = (_Float16)b;
  unsigned short ua, ub;
  __builtin_memcpy(&ua, &ha, 2); __builtin_memcpy(&ub, &hb, 2);
  return (unsigned)ua | ((unsigned)ub << 16);
}
__device__ __forceinline__ float upf16l(unsigned w) {
  unsigned short u = (unsigned short)(w & 0xFFFF);
  _Float16 h; __builtin_memcpy(&h, &u, 2); return (float)h;
}
__device__ __forceinline__ float upf16h(unsigned w) {
  unsigned short u = (unsigned short)(w >> 16);
  _Float16 h; __builtin_memcpy(&h, &u, 2); return (float)h;
}

// ---------------- kernel 1: weight fp32 [co][K] -> bf16 [K/8][co][8] --------
__global__ __launch_bounds__(256) void prep_w_kernel(const float* __restrict__ w,
                                                     unsigned short* __restrict__ wbf) {
  int idx = blockIdx.x * 256 + threadIdx.x;
  if (idx >= COUT * KTOT) return;
  int co = idx / KTOT;
  int K  = idx - co * KTOT;
  wbf[(K >> 3) * (COUT * 8) + co * 8 + (K & 7)] = f2bf(w[co * KTOT + K]);
}

// ---------------- kernel 2: fused desc-gen + LDS gather + MFMA GEMM ---------
__global__ __launch_bounds__(256, 4) void sphconv_kernel(
    const float* __restrict__ x, const unsigned short* __restrict__ wbf,
    const float* __restrict__ bias, float* __restrict__ out) {
  __shared__ __align__(16) unsigned short Sl[8 * PXT * 8];   // 16 KB [kg][px][j]
  __shared__ __align__(16) unsigned stg[4 * STG_CH];         // 21.4 KB bf16 pair-words

  const int tid  = threadIdx.x;
  const int ct   = blockIdx.x;          // 0..1
  const int r    = blockIdx.y;          // 0..127
  const int n    = blockIdx.z;          // 0..3
  const int c0   = ct * PXT;
  const int lane = tid & 63;
  const int wv   = tid >> 6;
  const int co_base = (wv & 1) * 64;
  const int px_base = (wv >> 1) * 64;
  const int rlo  = min(max(r - 2, 0), IMH - 5);

  // ---- phase 0: compute this thread's descriptors (f64, once) ----
  int opk[5], dkpx[5];
  unsigned wA[5], wB[5];   // f16-packed (w0,w1) and (w2,w3)
  {
    const double pi = 3.14159265358979323846;
    double dphi = pi / IMH;
    double dth  = 2.0 * pi / IMW;
    double t  = tan(dth);
    double p  = tan(dphi);
    double sp = p / cos(dth);
    double phi   = -(((double)r + 0.5) / IMH * pi - pi * 0.5);
    double sphi = sin(phi), cphi = cos(phi);
    #pragma unroll 1
    for (int dd = 0; dd < 5; dd++) {
      int d = tid + dd * 256;
      if (d >= NDPB) break;
      int px = d / 9, k = d - (d / 9) * 9;
      int c = c0 + px;
      int i = k / 3, j = k % 3;
      double theta = ((double)c + 0.5) / IMW * (2.0 * pi) - pi;
      double new_r, new_c;
      if (k == 4) {
        new_r = (double)r; new_c = (double)c;
      } else {
        double X = (j == 0) ? -t : ((j == 2) ? t : 0.0);
        double Y = 0.0;
        if (i == 0)      Y = (j == 1) ?  p :  sp;
        else if (i == 2) Y = (j == 1) ? -p : -sp;
        double rho = sqrt(X * X + Y * Y);
        double v   = atan(rho);
        double sv = sin(v), cv = cos(v);
        double arg = cv * sphi + Y * sv * cphi / rho;
        arg = fmin(1.0, fmax(-1.0, arg));
        double new_phi = asin(arg);
        double denom = rho * cphi * cv - Y * sphi * sv;
        double new_theta = theta + atan(X * sv / denom);
        new_r = (-new_phi + pi * 0.5) * IMH / pi - 0.5;
        new_c = (new_theta + pi) * IMW / (2.0 * pi) - 0.5;
        new_c = fmod(new_c + (double)IMW, (double)IMW);
      }
      float gx = (float)(new_c * 2.0 / IMW - 1.0);
      float gy = (float)(new_r * 2.0 / IMH - 1.0);
      float ix = ((gx + 1.0f) * (float)IMW - 1.0f) * 0.5f;
      float iy = ((gy + 1.0f) * (float)IMH - 1.0f) * 0.5f;
      float fx = floorf(ix), fy = floorf(iy);
      int x0 = (int)fx, y0 = (int)fy;
      float wx1 = ix - fx, wy1 = iy - fy;
      float wx0 = 1.0f - wx1, wy0 = 1.0f - wy1;
      int x1 = x0 + 1, y1 = y0 + 1;
      bool vx0 = (x0 >= 0) & (x0 <= IMW - 1);
      bool vx1 = (x1 >= 0) & (x1 <= IMW - 1);
      bool vy0 = (y0 >= 0) & (y0 <= IMH - 1);
      bool vy1 = (y1 >= 0) & (y1 <= IMH - 1);
      int y0c = min(max(y0, 0), IMH - 1), y1c = min(max(y1, 0), IMH - 1);
      int copy, widx;
      if (x0 < 0)        { copy = 0; widx = 0; }
      else if (x0 & 1)   { copy = 1; widx = (x0 - 1) >> 1; }
      else               { copy = 0; widx = x0 >> 1; }
      int col_lo = 2 * widx + copy;
      int col_hi = col_lo + 1;
      float wl = (col_lo == x0 && vx0) ? wx0 : ((col_lo == x1 && vx1) ? wx1 : 0.0f);
      float wh = (col_hi == x0 && vx0) ? wx0 : ((col_hi == x1 && vx1) ? wx1 : 0.0f);
      float wy0m = vy0 ? wy0 : 0.0f, wy1m = vy1 ? wy1 : 0.0f;
      int o_top = copy * STG_COPY + (y0c - rlo) * STG_ROW + widx;
      int o_bot = copy * STG_COPY + (y1c - rlo) * STG_ROW + widx;
      opk[dd]  = o_top | (o_bot << 16);
      wA[dd]   = pkf16(wy0m * wl, wy0m * wh);
      wB[dd]   = pkf16(wy1m * wl, wy1m * wh);
      dkpx[dd] = px | (k << 16);
    }
  }

  floatx4 acc[4][4];
  #pragma unroll
  for (int mt = 0; mt < 4; mt++)
    #pragma unroll
    for (int nt = 0; nt < 4; nt++)
      acc[mt][nt] = (floatx4){0.f, 0.f, 0.f, 0.f};

  const float* xn = x + (size_t)n * CIN * NPIX;

  #pragma unroll 1
  for (int cb = 0; cb < 9; cb++) {
    const int kb  = cb * 64;
    const int ci0 = kb / 9;
    __syncthreads();   // prev chunk's Sl/stg reads done
    #pragma unroll 1
    for (int h = 0; h < 2; h++) {
      const int cA = ci0 + 4 * h;
      if (h) __syncthreads();      // gather(h=0) done reading stg
      { // stage channel cA+wv, rows 0..4 (bf16, two shifted pair-copies)
        const float* src = xn + (size_t)(cA + wv) * NPIX + (size_t)rlo * IMW + lane * 4;
        unsigned* dstA = &stg[wv * STG_CH];
        unsigned* dstB = &stg[wv * STG_CH + STG_COPY];
        #pragma unroll
        for (int rw = 0; rw < 5; rw++) {
          float4 v = *(const float4*)(src + rw * IMW);
          float c4 = 0.0f;
          if (lane < 63) c4 = src[rw * IMW + 4];   // guarded: no OOB on last plane
          uint2 wa; wa.x = pk2(v.x, v.y); wa.y = pk2(v.z, v.w);
          uint2 wb; wb.x = pk2(v.y, v.z); wb.y = pk2(v.w, c4);
          *(uint2*)&dstA[rw * STG_ROW + 2 * lane] = wa;
          *(uint2*)&dstB[rw * STG_ROW + 2 * lane] = wb;
        }
      }
      __syncthreads();             // stg half ready
      // gather this half's channels into Sl
      #pragma unroll
      for (int dd = 0; dd < 5; dd++) {
        int d = tid + dd * 256;
        if (d < NDPB) {
          const int px = dkpx[dd] & 0xFFFF, k = dkpx[dd] >> 16;
          float w0 = upf16l(wA[dd]), w1 = upf16h(wA[dd]);
          float w2 = upf16l(wB[dd]), w3 = upf16h(wB[dd]);
          int ci_lo = (kb - k + 8) / 9;
          int ci_hi = (kb + 63 - k) / 9 + 1; if (ci_hi > CIN) ci_hi = CIN;
          const unsigned* ptop = &stg[opk[dd] & 0xFFFF];
          const unsigned* pbot = &stg[((unsigned)opk[dd]) >> 16];
          #pragma unroll
          for (int chl = 0; chl < 4; chl++) {
            int ci = cA + chl;
            if (ci >= ci_lo && ci < ci_hi) {
              unsigned wt  = ptop[chl * STG_CH];
              unsigned wb_ = pbot[chl * STG_CH];
              float s = w0 * bfl(wt) + w1 * bfh(wt)
                      + w2 * bfl(wb_) + w3 * bfh(wb_);
              int kk = ci * 9 + k - kb;   // 0..63
              Sl[((kk >> 3) * PXT + px) * 8 + (kk & 7)] = f2bf(s);
            }
          }
        }
      }
    }
    __syncthreads();   // Sl complete
    // MFMA: A-fragments straight from global (L2/L1-resident wbf)
    #pragma unroll
    for (int ks = 0; ks < 2; ks++) {
      const int kg = ks * 4 + (lane >> 4);
      const unsigned short* arow = wbf + ((cb * 8 + kg) * COUT + co_base + (lane & 15)) * 8;
      #pragma unroll
      for (int nt = 0; nt < 4; nt++) {
        short8 b = *(const short8*)&Sl[((kg * PXT) + px_base + nt * 16 + (lane & 15)) * 8];
        #pragma unroll
        for (int mt = 0; mt < 4; mt++) {
          short8 a = *(const short8*)(arow + mt * 16 * 8);
          acc[mt][nt] = __builtin_amdgcn_mfma_f32_16x16x32_bf16(a, b, acc[mt][nt], 0, 0, 0);
        }
      }
    }
  }

  // epilogue: D row = co, col = px (row=(lane>>4)*4+reg, col=lane&15)
  #pragma unroll
  for (int mt = 0; mt < 4; mt++) {
    #pragma unroll
    for (int nt = 0; nt < 4; nt++) {
      #pragma unroll
      for (int rg = 0; rg < 4; rg++) {
        const int co = co_base + mt * 16 + (lane >> 4) * 4 + rg;
        const int cc = c0 + px_base + nt * 16 + (lane & 15);
        out[(((size_t)n * COUT + co) * IMH + r) * IMW + cc] = acc[mt][nt][rg] + bias[co];
      }
    }
  }
}

extern "C" void kernel_launch(void* const* d_in, const int* in_sizes, int n_in,
                              void* d_out, int out_size, void* d_ws, size_t ws_size,
                              hipStream_t stream) {
  const float* x    = (const float*)d_in[0];
  const float* w    = (const float*)d_in[1];
  const float* bias = (const float*)d_in[2];
  float* out = (float*)d_out;
  unsigned short* wbf = (unsigned short*)d_ws;   // 147 KB
  (void)in_sizes; (void)n_in; (void)out_size; (void)ws_size;

  hipLaunchKernelGGL(prep_w_kernel, dim3((COUT * KTOT + 255) / 256), dim3(256), 0, stream, w, wbf);
  hipLaunchKernelGGL(sphconv_kernel, dim3(IMW / PXT, IMH, NB), dim3(256), 0, stream,
                     x, wbf, bias, out);
}

// Round 5
// 209.573 us; speedup vs baseline: 1.4283x; 1.4283x over previous
//
#include <hip/hip_runtime.h>
#include <math.h>

typedef __attribute__((ext_vector_type(8))) short short8;
typedef __attribute__((ext_vector_type(4))) float floatx4;

#define NB    4
#define CIN   64
#define COUT  128
#define IMH   128
#define IMW   256
#define KTOT  576
#define NPIX  (IMH * IMW)
#define PXT   128
#define NDPB  (PXT * 9)          // 1152 descriptors per block
#define STG_ROW  134             // words per staged row (128 data + pad)
#define STG_COPY (5 * STG_ROW)   // 670
#define STG_CH   (2 * STG_COPY)  // 1340 words per channel

__device__ __forceinline__ unsigned short f2bf(float f) {
  union { float f; unsigned u; } v; v.f = f;
  return (unsigned short)((v.u + 0x7FFFu + ((v.u >> 16) & 1u)) >> 16);
}
__device__ __forceinline__ unsigned pk2(float lo, float hi) {
  return (unsigned)f2bf(lo) | ((unsigned)f2bf(hi) << 16);
}
__device__ __forceinline__ float bfl(unsigned w) {
  union { unsigned u; float f; } v; v.u = w << 16; return v.f;
}
__device__ __forceinline__ float bfh(unsigned w) {
  union { unsigned u; float f; } v; v.u = w & 0xFFFF0000u; return v.f;
}
__device__ __forceinline__ unsigned pkf16(float a, float b) {
  _Float16 ha = (_Float16)a, hb = (_Float16)b;
  unsigned short ua, ub;
  __builtin_memcpy(&ua, &ha, 2); __builtin_memcpy(&ub, &hb, 2);
  return (unsigned)ua | ((unsigned)ub << 16);
}
__device__ __forceinline__ float upf16l(unsigned w) {
  unsigned short u = (unsigned short)(w & 0xFFFF);
  _Float16 h; __builtin_memcpy(&h, &u, 2); return (float)h;
}
__device__ __forceinline__ float upf16h(unsigned w) {
  unsigned short u = (unsigned short)(w >> 16);
  _Float16 h; __builtin_memcpy(&h, &u, 2); return (float)h;
}

// ---------------- kernel 1: weight fp32 [co][K] -> bf16 [K/8][co][8] --------
__global__ __launch_bounds__(256) void prep_w_kernel(const float* __restrict__ w,
                                                     unsigned short* __restrict__ wbf) {
  int idx = blockIdx.x * 256 + threadIdx.x;
  if (idx >= COUT * KTOT) return;
  int co = idx / KTOT;
  int K  = idx - co * KTOT;
  wbf[(K >> 3) * (COUT * 8) + co * 8 + (K & 7)] = f2bf(w[co * KTOT + K]);
}

// ------- kernel 2: fused desc-gen + 8-wave LDS gather + MFMA GEMM -----------
// 512 threads = 8 waves; wave computes 32co x 64px (acc 2x4 tiles = 32 AGPR).
// __launch_bounds__(512,4): 4 waves/EU -> 2 blocks/CU, 128-reg/wave budget
// (32 acc + ~90 arch fits; R4's (256,4) with 64-AGPR acc spilled ~570 MB).
__global__ __launch_bounds__(512, 4) void sphconv_kernel(
    const float* __restrict__ x, const unsigned short* __restrict__ wbf,
    const float* __restrict__ bias, float* __restrict__ out) {
  __shared__ __align__(16) unsigned short Sl[8 * PXT * 8];   // 16 KB [kg][px][j]
  __shared__ __align__(16) unsigned stg[8 * STG_CH];         // 42.9 KB, 8 channels

  const int tid  = threadIdx.x;
  const int ct   = blockIdx.x;          // 0..1
  const int r    = blockIdx.y;          // 0..127
  const int n    = blockIdx.z;          // 0..3
  const int c0   = ct * PXT;
  const int lane = tid & 63;
  const int wv   = tid >> 6;            // 0..7
  const int co_base = (wv & 3) * 32;
  const int px_base = (wv >> 2) * 64;
  const int rlo  = min(max(r - 2, 0), IMH - 5);

  // ---- phase 0: this thread's descriptors (f64 trig, once) ----
  int opk[3], dkpx[3];
  unsigned wA[3], wB[3];   // f16-packed (w0,w1), (w2,w3)
  {
    const double pi = 3.14159265358979323846;
    double dphi = pi / IMH;
    double dth  = 2.0 * pi / IMW;
    double t  = tan(dth);
    double p  = tan(dphi);
    double sp = p / cos(dth);
    double phi   = -(((double)r + 0.5) / IMH * pi - pi * 0.5);
    double sphi = sin(phi), cphi = cos(phi);
    #pragma unroll 1
    for (int dd = 0; dd < 3; dd++) {
      int d = tid + dd * 512;
      if (d >= NDPB) break;
      int px = d / 9, k = d - (d / 9) * 9;
      int c = c0 + px;
      int i = k / 3, j = k % 3;
      double theta = ((double)c + 0.5) / IMW * (2.0 * pi) - pi;
      double new_r, new_c;
      if (k == 4) {
        new_r = (double)r; new_c = (double)c;
      } else {
        double X = (j == 0) ? -t : ((j == 2) ? t : 0.0);
        double Y = 0.0;
        if (i == 0)      Y = (j == 1) ?  p :  sp;
        else if (i == 2) Y = (j == 1) ? -p : -sp;
        double rho = sqrt(X * X + Y * Y);
        double v   = atan(rho);
        double sv = sin(v), cv = cos(v);
        double arg = cv * sphi + Y * sv * cphi / rho;
        arg = fmin(1.0, fmax(-1.0, arg));
        double new_phi = asin(arg);
        double denom = rho * cphi * cv - Y * sphi * sv;
        double new_theta = theta + atan(X * sv / denom);
        new_r = (-new_phi + pi * 0.5) * IMH / pi - 0.5;
        new_c = (new_theta + pi) * IMW / (2.0 * pi) - 0.5;
        new_c = fmod(new_c + (double)IMW, (double)IMW);
      }
      float gx = (float)(new_c * 2.0 / IMW - 1.0);
      float gy = (float)(new_r * 2.0 / IMH - 1.0);
      float ix = ((gx + 1.0f) * (float)IMW - 1.0f) * 0.5f;
      float iy = ((gy + 1.0f) * (float)IMH - 1.0f) * 0.5f;
      float fx = floorf(ix), fy = floorf(iy);
      int x0 = (int)fx, y0 = (int)fy;
      float wx1 = ix - fx, wy1 = iy - fy;
      float wx0 = 1.0f - wx1, wy0 = 1.0f - wy1;
      int x1 = x0 + 1, y1 = y0 + 1;
      bool vx0 = (x0 >= 0) & (x0 <= IMW - 1);
      bool vx1 = (x1 >= 0) & (x1 <= IMW - 1);
      bool vy0 = (y0 >= 0) & (y0 <= IMH - 1);
      bool vy1 = (y1 >= 0) & (y1 <= IMH - 1);
      int y0c = min(max(y0, 0), IMH - 1), y1c = min(max(y1, 0), IMH - 1);
      int copy, widx;
      if (x0 < 0)        { copy = 0; widx = 0; }
      else if (x0 & 1)   { copy = 1; widx = (x0 - 1) >> 1; }
      else               { copy = 0; widx = x0 >> 1; }
      int col_lo = 2 * widx + copy;
      int col_hi = col_lo + 1;
      float wl = (col_lo == x0 && vx0) ? wx0 : ((col_lo == x1 && vx1) ? wx1 : 0.0f);
      float wh = (col_hi == x0 && vx0) ? wx0 : ((col_hi == x1 && vx1) ? wx1 : 0.0f);
      float wy0m = vy0 ? wy0 : 0.0f, wy1m = vy1 ? wy1 : 0.0f;
      int o_top = copy * STG_COPY + (y0c - rlo) * STG_ROW + widx;
      int o_bot = copy * STG_COPY + (y1c - rlo) * STG_ROW + widx;
      opk[dd]  = o_top | (o_bot << 16);
      wA[dd]   = pkf16(wy0m * wl, wy0m * wh);
      wB[dd]   = pkf16(wy1m * wl, wy1m * wh);
      dkpx[dd] = px | (k << 16);
    }
  }

  floatx4 acc[2][4];
  #pragma unroll
  for (int mt = 0; mt < 2; mt++)
    #pragma unroll
    for (int nt = 0; nt < 4; nt++)
      acc[mt][nt] = (floatx4){0.f, 0.f, 0.f, 0.f};

  const float* xn = x + (size_t)n * CIN * NPIX;

  #pragma unroll 1
  for (int cb = 0; cb < 9; cb++) {
    const int kb  = cb * 64;
    const int ci0 = kb / 9;      // chunk needs exactly channels ci0..ci0+7
    __syncthreads();             // prev chunk's stg/Sl reads done
    { // stage channel ci0+wv (<=63), rows 0..4, two shifted bf16 pair-copies
      const float* src = xn + (size_t)(ci0 + wv) * NPIX + (size_t)rlo * IMW + lane * 4;
      unsigned* dstA = &stg[wv * STG_CH];
      unsigned* dstB = &stg[wv * STG_CH + STG_COPY];
      #pragma unroll
      for (int rw = 0; rw < 5; rw++) {
        float4 v = *(const float4*)(src + rw * IMW);
        float c4 = 0.0f;
        if (lane < 63) c4 = src[rw * IMW + 4];   // guarded: no OOB on last plane
        uint2 wa; wa.x = pk2(v.x, v.y); wa.y = pk2(v.z, v.w);
        uint2 wb; wb.x = pk2(v.y, v.z); wb.y = pk2(v.w, c4);
        *(uint2*)&dstA[rw * STG_ROW + 2 * lane] = wa;
        *(uint2*)&dstB[rw * STG_ROW + 2 * lane] = wb;
      }
    }
    __syncthreads();             // stg ready
    // gather all 8 channels into Sl
    #pragma unroll
    for (int dd = 0; dd < 3; dd++) {
      int d = tid + dd * 512;
      if (d < NDPB) {
        const int px = dkpx[dd] & 0xFFFF, k = dkpx[dd] >> 16;
        float w0 = upf16l(wA[dd]), w1 = upf16h(wA[dd]);
        float w2 = upf16l(wB[dd]), w3 = upf16h(wB[dd]);
        int ci_lo = (kb - k + 8) / 9;
        int ci_hi = (kb + 63 - k) / 9 + 1; if (ci_hi > CIN) ci_hi = CIN;
        const unsigned* ptop = &stg[opk[dd] & 0xFFFF];
        const unsigned* pbot = &stg[((unsigned)opk[dd]) >> 16];
        #pragma unroll
        for (int chl = 0; chl < 8; chl++) {
          int ci = ci0 + chl;
          if (ci >= ci_lo && ci < ci_hi) {
            unsigned wt  = ptop[chl * STG_CH];
            unsigned wb_ = pbot[chl * STG_CH];
            float s = w0 * bfl(wt) + w1 * bfh(wt)
                    + w2 * bfl(wb_) + w3 * bfh(wb_);
            int kk = ci * 9 + k - kb;   // 0..63
            Sl[((kk >> 3) * PXT + px) * 8 + (kk & 7)] = f2bf(s);
          }
        }
      }
    }
    __syncthreads();             // Sl complete
    // MFMA: A-fragments straight from global (L2-resident wbf)
    #pragma unroll
    for (int ks = 0; ks < 2; ks++) {
      const int kg = ks * 4 + (lane >> 4);
      const unsigned short* arow = wbf + ((cb * 8 + kg) * COUT + co_base + (lane & 15)) * 8;
      #pragma unroll
      for (int nt = 0; nt < 4; nt++) {
        short8 b = *(const short8*)&Sl[((kg * PXT) + px_base + nt * 16 + (lane & 15)) * 8];
        #pragma unroll
        for (int mt = 0; mt < 2; mt++) {
          short8 a = *(const short8*)(arow + mt * 16 * 8);
          acc[mt][nt] = __builtin_amdgcn_mfma_f32_16x16x32_bf16(a, b, acc[mt][nt], 0, 0, 0);
        }
      }
    }
  }

  // epilogue: D row = co, col = px (row=(lane>>4)*4+reg, col=lane&15)
  #pragma unroll
  for (int mt = 0; mt < 2; mt++) {
    #pragma unroll
    for (int nt = 0; nt < 4; nt++) {
      #pragma unroll
      for (int rg = 0; rg < 4; rg++) {
        const int co = co_base + mt * 16 + (lane >> 4) * 4 + rg;
        const int cc = c0 + px_base + nt * 16 + (lane & 15);
        out[(((size_t)n * COUT + co) * IMH + r) * IMW + cc] = acc[mt][nt][rg] + bias[co];
      }
    }
  }
}

extern "C" void kernel_launch(void* const* d_in, const int* in_sizes, int n_in,
                              void* d_out, int out_size, void* d_ws, size_t ws_size,
                              hipStream_t stream) {
  const float* x    = (const float*)d_in[0];
  const float* w    = (const float*)d_in[1];
  const float* bias = (const float*)d_in[2];
  float* out = (float*)d_out;
  unsigned short* wbf = (unsigned short*)d_ws;   // 147 KB
  (void)in_sizes; (void)n_in; (void)out_size; (void)ws_size;

  hipLaunchKernelGGL(prep_w_kernel, dim3((COUT * KTOT + 255) / 256), dim3(256), 0, stream, w, wbf);
  hipLaunchKernelGGL(sphconv_kernel, dim3(IMW / PXT, IMH, NB), dim3(512), 0, stream,
                     x, wbf, bias, out);
}

// Round 6
// 195.726 us; speedup vs baseline: 1.5293x; 1.0707x over previous
//
#include <hip/hip_runtime.h>
#include <math.h>

typedef __attribute__((ext_vector_type(8))) short short8;
typedef __attribute__((ext_vector_type(4))) float floatx4;

#define NB    4
#define CIN   64
#define COUT  128
#define IMH   128
#define IMW   256
#define KTOT  576
#define NPIX  (IMH * IMW)
#define PXT   128
#define NDPB  (PXT * 9)      // 1152 descriptors per block
#define SROW  260            // staged row stride, f32 words (1040 B, 16B-aligned)
#define SCH   (5 * SROW)     // 1300 words per channel
#define SLSTR 72             // Sl stride (elements) per px; 144 B, 16B-aligned

__device__ __forceinline__ unsigned short f2bf(float f) {
  union { float f; unsigned u; } v; v.f = f;
  return (unsigned short)((v.u + 0x7FFFu + ((v.u >> 16) & 1u)) >> 16);
}
__device__ __forceinline__ unsigned pkf16(float a, float b) {
  _Float16 ha = (_Float16)a, hb = (_Float16)b;
  unsigned short ua, ub;
  __builtin_memcpy(&ua, &ha, 2); __builtin_memcpy(&ub, &hb, 2);
  return (unsigned)ua | ((unsigned)ub << 16);
}
__device__ __forceinline__ float upf16l(unsigned w) {
  unsigned short u = (unsigned short)(w & 0xFFFF);
  _Float16 h; __builtin_memcpy(&h, &u, 2); return (float)h;
}
__device__ __forceinline__ float upf16h(unsigned w) {
  unsigned short u = (unsigned short)(w >> 16);
  _Float16 h; __builtin_memcpy(&h, &u, 2); return (float)h;
}

// ---------------- kernel 1: weight fp32 [co][K] -> bf16 [K/8][co][8] --------
__global__ __launch_bounds__(256) void prep_w_kernel(const float* __restrict__ w,
                                                     unsigned short* __restrict__ wbf) {
  int idx = blockIdx.x * 256 + threadIdx.x;
  if (idx >= COUT * KTOT) return;
  int co = idx / KTOT;
  int K  = idx - co * KTOT;
  wbf[(K >> 3) * (COUT * 8) + co * 8 + (K & 7)] = f2bf(w[co * KTOT + K]);
}

// ------- kernel 2: fused desc-gen + f32 LDS-staged gather + MFMA GEMM -------
// 512 thr = 8 waves; wave = 64co x 32px (acc[4][2] = 32 AGPR).
// (512,4): 4 waves/EU -> 2 blocks/CU @ 128-reg budget (no spills, per R5).
__global__ __launch_bounds__(512, 4) void sphconv_kernel(
    const float* __restrict__ x, const unsigned short* __restrict__ wbf,
    const float* __restrict__ bias, float* __restrict__ out) {
  __shared__ __align__(16) float stg[8 * SCH];               // 41.6 KB f32
  __shared__ __align__(16) unsigned short Sl[PXT * SLSTR];   // 18.4 KB [px][kk]

  const int tid  = threadIdx.x;
  const int ct   = blockIdx.x;          // 0..1
  const int r    = blockIdx.y;          // 0..127
  const int n    = blockIdx.z;          // 0..3
  const int c0   = ct * PXT;
  const int lane = tid & 63;
  const int wv   = tid >> 6;            // 0..7
  const int co_base = (wv & 1) * 64;
  const int px_base = (wv >> 1) * 32;
  const int rlo  = min(max(r - 2, 0), IMH - 5);

  // ---- phase 0: this thread's descriptors (f64 trig, once) ----
  int opk[3], dkpx[3];
  unsigned wA[3], wB[3];   // f16-packed (w_lo,w_hi) for top and bottom rows
  {
    const double pi = 3.14159265358979323846;
    double dphi = pi / IMH;
    double dth  = 2.0 * pi / IMW;
    double t  = tan(dth);
    double p  = tan(dphi);
    double sp = p / cos(dth);
    double phi   = -(((double)r + 0.5) / IMH * pi - pi * 0.5);
    double sphi = sin(phi), cphi = cos(phi);
    #pragma unroll 1
    for (int dd = 0; dd < 3; dd++) {
      int d = tid + dd * 512;
      if (d >= NDPB) break;
      int px = d / 9, k = d - (d / 9) * 9;
      int c = c0 + px;
      int i = k / 3, j = k % 3;
      double theta = ((double)c + 0.5) / IMW * (2.0 * pi) - pi;
      double new_r, new_c;
      if (k == 4) {
        new_r = (double)r; new_c = (double)c;
      } else {
        double X = (j == 0) ? -t : ((j == 2) ? t : 0.0);
        double Y = 0.0;
        if (i == 0)      Y = (j == 1) ?  p :  sp;
        else if (i == 2) Y = (j == 1) ? -p : -sp;
        double rho = sqrt(X * X + Y * Y);
        double v   = atan(rho);
        double sv = sin(v), cv = cos(v);
        double arg = cv * sphi + Y * sv * cphi / rho;
        arg = fmin(1.0, fmax(-1.0, arg));
        double new_phi = asin(arg);
        double denom = rho * cphi * cv - Y * sphi * sv;
        double new_theta = theta + atan(X * sv / denom);
        new_r = (-new_phi + pi * 0.5) * IMH / pi - 0.5;
        new_c = (new_theta + pi) * IMW / (2.0 * pi) - 0.5;
        new_c = fmod(new_c + (double)IMW, (double)IMW);
      }
      float gx = (float)(new_c * 2.0 / IMW - 1.0);
      float gy = (float)(new_r * 2.0 / IMH - 1.0);
      float ix = ((gx + 1.0f) * (float)IMW - 1.0f) * 0.5f;
      float iy = ((gy + 1.0f) * (float)IMH - 1.0f) * 0.5f;
      float fx = floorf(ix), fy = floorf(iy);
      int x0 = (int)fx, y0 = (int)fy;
      float wx1 = ix - fx, wy1 = iy - fy;
      float wx0 = 1.0f - wx1, wy0 = 1.0f - wy1;
      int x1 = x0 + 1, y1 = y0 + 1;
      // ix in [-0.5, 255.5) => x0 in [-1,255], x1 in [0,256]
      bool vy0 = (y0 >= 0) & (y0 <= IMH - 1);
      bool vy1 = (y1 >= 0) & (y1 <= IMH - 1);
      int y0c = min(max(y0, 0), IMH - 1), y1c = min(max(y1, 0), IMH - 1);
      int x0c = max(x0, 0);                       // cols read: x0c, x0c+1 (<=256 pad)
      float w_lo = (x0 >= 0) ? wx0 : wx1;         // x0=-1: col0 == x1
      float w_hi = (x0 >= 0) ? ((x1 <= IMW - 1) ? wx1 : 0.0f) : 0.0f;
      float wy0m = vy0 ? wy0 : 0.0f, wy1m = vy1 ? wy1 : 0.0f;
      int o_top = (y0c - rlo) * SROW + x0c;       // <= 4*260+255 = 1295
      int o_bot = (y1c - rlo) * SROW + x0c;
      opk[dd]  = o_top | (o_bot << 16);
      wA[dd]   = pkf16(wy0m * w_lo, wy0m * w_hi);
      wB[dd]   = pkf16(wy1m * w_lo, wy1m * w_hi);
      dkpx[dd] = px | (k << 16);
    }
  }

  floatx4 acc[4][2];
  #pragma unroll
  for (int mt = 0; mt < 4; mt++)
    #pragma unroll
    for (int nt = 0; nt < 2; nt++)
      acc[mt][nt] = (floatx4){0.f, 0.f, 0.f, 0.f};

  const float* xn = x + (size_t)n * CIN * NPIX;

  #pragma unroll 1
  for (int cb = 0; cb < 9; cb++) {
    const int kb  = cb * 64;
    const int ci0 = kb / 9;      // chunk uses exactly channels ci0..ci0+7 (<=63)
    __syncthreads();             // prev chunk's stg/Sl reads done
    { // stage channel ci0+wv, rows 0..4, f32 single copy
      const float* src = xn + (size_t)(ci0 + wv) * NPIX + (size_t)rlo * IMW + lane * 4;
      float* dch = &stg[wv * SCH];
      #pragma unroll
      for (int rw = 0; rw < 5; rw++)
        *(float4*)&dch[rw * SROW + lane * 4] = *(const float4*)(src + rw * IMW);
      if (lane == 0) {           // zero pad col 256 (read when x0==255, weight 0)
        #pragma unroll
        for (int rw = 0; rw < 5; rw++) dch[rw * SROW + 256] = 0.0f;
      }
    }
    __syncthreads();             // stg ready
    // gather all 8 channels into Sl[px][kk]
    #pragma unroll
    for (int dd = 0; dd < 3; dd++) {
      int d = tid + dd * 512;
      if (d < NDPB) {
        const int px = dkpx[dd] & 0xFFFF, k = dkpx[dd] >> 16;
        const float w0 = upf16l(wA[dd]), w1 = upf16h(wA[dd]);
        const float w2 = upf16l(wB[dd]), w3 = upf16h(wB[dd]);
        const float* pt = &stg[opk[dd] & 0xFFFF];
        const float* pb = &stg[((unsigned)opk[dd]) >> 16];
        const int kbase = ci0 * 9 + k - kb;        // kk for chl=0
        unsigned short* sw = &Sl[px * SLSTR + kbase];
        #pragma unroll
        for (int chl = 0; chl < 8; chl++) {
          int kk = kbase + 9 * chl;
          if ((unsigned)kk < 64u) {                // in-chunk & ci valid
            float s = w0 * pt[chl * SCH] + w1 * pt[chl * SCH + 1]
                    + w2 * pb[chl * SCH] + w3 * pb[chl * SCH + 1];
            sw[9 * chl] = f2bf(s);                 // immediate-offset b16 write
          }
        }
      }
    }
    __syncthreads();             // Sl complete
    // MFMA: A-frags from global (L2-resident wbf), B-frags from Sl
    #pragma unroll
    for (int ks = 0; ks < 2; ks++) {
      const int kg = ks * 4 + (lane >> 4);
      const unsigned short* arow = wbf + ((cb * 8 + kg) * COUT + co_base + (lane & 15)) * 8;
      #pragma unroll
      for (int nt = 0; nt < 2; nt++) {
        short8 b = *(const short8*)&Sl[(px_base + nt * 16 + (lane & 15)) * SLSTR
                                       + ks * 32 + (lane >> 4) * 8];
        #pragma unroll
        for (int mt = 0; mt < 4; mt++) {
          short8 a = *(const short8*)(arow + mt * 16 * 8);
          acc[mt][nt] = __builtin_amdgcn_mfma_f32_16x16x32_bf16(a, b, acc[mt][nt], 0, 0, 0);
        }
      }
    }
  }

  // epilogue: D row = co (row=(lane>>4)*4+reg), col = px (lane&15)
  #pragma unroll
  for (int mt = 0; mt < 4; mt++) {
    #pragma unroll
    for (int nt = 0; nt < 2; nt++) {
      #pragma unroll
      for (int rg = 0; rg < 4; rg++) {
        const int co = co_base + mt * 16 + (lane >> 4) * 4 + rg;
        const int cc = c0 + px_base + nt * 16 + (lane & 15);
        out[(((size_t)n * COUT + co) * IMH + r) * IMW + cc] = acc[mt][nt][rg] + bias[co];
      }
    }
  }
}

extern "C" void kernel_launch(void* const* d_in, const int* in_sizes, int n_in,
                              void* d_out, int out_size, void* d_ws, size_t ws_size,
                              hipStream_t stream) {
  const float* x    = (const float*)d_in[0];
  const float* w    = (const float*)d_in[1];
  const float* bias = (const float*)d_in[2];
  float* out = (float*)d_out;
  unsigned short* wbf = (unsigned short*)d_ws;   // 147 KB
  (void)in_sizes; (void)n_in; (void)out_size; (void)ws_size;

  hipLaunchKernelGGL(prep_w_kernel, dim3((COUT * KTOT + 255) / 256), dim3(256), 0, stream, w, wbf);
  hipLaunchKernelGGL(sphconv_kernel, dim3(IMW / PXT, IMH, NB), dim3(512), 0, stream,
                     x, wbf, bias, out);
}